// Round 15
// baseline (73.594 us; speedup 1.0000x reference)
//
#include <hip/hip_runtime.h>

#define B_    32
#define S_    512
#define ND_   4096   // N*D = 64*64
#define ND4_  1024
#define SCH   16     // s-chunks per batch (512 blocks = 2/CU, r12 champion config)
#define CH    32     // rows per block (S_/SCH), processed cooperatively
#define NPH   (CH/2) // 2 rows per barrier phase
#define NUNIT (B_ * SCH)

typedef float f4 __attribute__((ext_vector_type(4)));
typedef float f2 __attribute__((ext_vector_type(2)));

// ws float layout: num[B_*ND_] | den[B_] (+pad to 64) | qw[ND_]
#define DEN_OFF (B_ * ND_)
#define QW_OFF  (DEN_OFF + 64)

// qw[n,d] = (sum_e (q_embed[n,:] . Wq_w[e,:] + Wq_b[e]) * Wkv_w[e,d]) / sqrt(D)
// Also zeroes num/den accumulators every launch (graph-replay deterministic).
__global__ void qw_kernel(const float* __restrict__ qe, const float* __restrict__ Wq_w,
                          const float* __restrict__ Wq_b, const float* __restrict__ Wkv_w,
                          float* __restrict__ ws) {
    const int n = blockIdx.x;   // 64 blocks
    const int t = threadIdx.x;  // 64 threads
    // zero num: 32768 f4 across 4096 threads -> 8 each
    {
        f4* num4 = (f4*)ws;
        const int base = n * 64 + t;
#pragma unroll
        for (int i = 0; i < 8; ++i) num4[base + i * 4096] = (f4)(0.f);
        if (n == 0 && t < B_) ws[DEN_OFF + t] = 0.f;
    }
    __shared__ float qrow[64];
    float acc = Wq_b[t];
    const float* qen = qe + n * 64;
    const float* wqr = Wq_w + t * 64;   // q[n,e] = sum_d qe[n,d]*Wq_w[e,d] + b[e]
#pragma unroll 8
    for (int d = 0; d < 64; ++d) acc += qen[d] * wqr[d];
    qrow[t] = acc;
    __syncthreads();
    float s = 0.f;
#pragma unroll 8
    for (int e = 0; e < 64; ++e) s += qrow[e] * Wkv_w[e * 64 + t];  // k half only
    ws[QW_OFF + n * 64 + t] = s * 0.125f;  // 1/sqrt(64)
}

// Cooperative-row flash (r12 structure, untouched loop): 2 rows per barrier
// phase, fixed-max softmax (m=8, clamp 52), raw s_barrier + lgkmcnt-only wait
// + sched_barrier(0) pin. Tail: flat atomicAdd of o[] into num[b][:] and lsum
// into den[b] — no LDS merge, no fence, no po round-trip, no combine read.
__global__ __launch_bounds__(256) void flash_partial(
    const float* __restrict__ x, float* __restrict__ ws) {
    const float* qw = ws + QW_OFF;
    float* num = ws;
    float* den = ws + DEN_OFF;

    const int blk = blockIdx.x;
    const int b   = blk >> 4;        // / SCH
    const int c   = blk & (SCH - 1);
    const int t   = threadIdx.x;
    const int w   = t >> 6;          // wave 0..3
    const int l   = t & 63;

    __shared__ f2 red[2][4];

    const f4* qw4 = (const f4*)qw;
    f4 qv[4];
#pragma unroll
    for (int k = 0; k < 4; ++k) qv[k] = qw4[k * 256 + t];

    f4 o[4];
#pragma unroll
    for (int k = 0; k < 4; ++k) o[k] = (f4)(0.f);
    float lsum = 0.f;

    const f4* xb = (const f4*)x + (size_t)(b * S_ + c * CH) * ND4_;

    f4 cur[2][4], nxt[2][4];
#pragma unroll
    for (int rr = 0; rr < 2; ++rr)
#pragma unroll
        for (int k = 0; k < 4; ++k) cur[rr][k] = xb[(size_t)rr * ND4_ + k * 256 + t];

    for (int ph = 0; ph < NPH; ++ph) {
        // prefetch next pair BEFORE the barrier region: rides in flight across it
        if (ph + 1 < NPH) {
            const f4* xn = xb + (size_t)(2 * ph + 2) * ND4_;
#pragma unroll
            for (int rr = 0; rr < 2; ++rr)
#pragma unroll
                for (int k = 0; k < 4; ++k) nxt[rr][k] = xn[(size_t)rr * ND4_ + k * 256 + t];
        }

        float pd0 = 0.f, pd1 = 0.f;
#pragma unroll
        for (int k = 0; k < 4; ++k) {
            pd0 += cur[0][k][0] * qv[k][0] + cur[0][k][1] * qv[k][1] +
                   cur[0][k][2] * qv[k][2] + cur[0][k][3] * qv[k][3];
            pd1 += cur[1][k][0] * qv[k][0] + cur[1][k][1] * qv[k][1] +
                   cur[1][k][2] * qv[k][2] + cur[1][k][3] * qv[k][3];
        }
#pragma unroll
        for (int off = 32; off > 0; off >>= 1) {
            pd0 += __shfl_xor(pd0, off, 64);
            pd1 += __shfl_xor(pd1, off, 64);
        }

        const int par = ph & 1;
        if (l == 0) { f2 v = { pd0, pd1 }; red[par][w] = v; }
        asm volatile("s_waitcnt lgkmcnt(0)" ::: "memory");  // red-write visible
        __builtin_amdgcn_s_barrier();
        __builtin_amdgcn_sched_barrier(0);                  // no hoist above barrier
        const f2 pr = red[par][0] + red[par][1] + red[par][2] + red[par][3];

        const float e0 = __expf(fminf(pr[0] - 8.f, 52.f));  // fixed max; clamp dead for real data
        const float e1 = __expf(fminf(pr[1] - 8.f, 52.f));
        lsum += e0 + e1;
#pragma unroll
        for (int k = 0; k < 4; ++k) o[k] += e0 * cur[0][k] + e1 * cur[1][k];

        if (ph + 1 < NPH) {
#pragma unroll
            for (int rr = 0; rr < 2; ++rr)
#pragma unroll
                for (int k = 0; k < 4; ++k) cur[rr][k] = nxt[rr][k];
        }
    }

    // flat atomic accumulate: num[b][elem], elem = (k*256+t)*4 + j
    float* nb = num + (size_t)b * ND_;
#pragma unroll
    for (int k = 0; k < 4; ++k) {
        const int e4 = (k * 256 + t) * 4;
        atomicAdd(nb + e4 + 0, o[k][0]);
        atomicAdd(nb + e4 + 1, o[k][1]);
        atomicAdd(nb + e4 + 2, o[k][2]);
        atomicAdd(nb + e4 + 3, o[k][3]);
    }
    if (t == 0) atomicAdd(den + b, lsum);   // lsum block-uniform; one add per block
}

// out[b][i] = num[b][i] / den[b]   — 128 blocks x 256 thr, one f4 each
__global__ __launch_bounds__(256) void divide_kernel(
    const float* __restrict__ ws, float* __restrict__ out) {
    const int idx4 = blockIdx.x * 256 + threadIdx.x;   // [0, 32768)
    const int b    = idx4 >> 10;
    const float inv = 1.f / ws[DEN_OFF + b];
    ((f4*)out)[idx4] = ((const f4*)ws)[idx4] * inv;
}

extern "C" void kernel_launch(void* const* d_in, const int* in_sizes, int n_in,
                              void* d_out, int out_size, void* d_ws, size_t ws_size,
                              hipStream_t stream) {
    const float* x     = (const float*)d_in[0];
    const float* qe    = (const float*)d_in[1];
    const float* Wq_w  = (const float*)d_in[2];
    const float* Wq_b  = (const float*)d_in[3];
    const float* Wkv_w = (const float*)d_in[4];
    // d_in[5] = Wkv_b: shifts prod by a per-(b,s)-uniform constant -> softmax-invariant.
    float* out = (float*)d_out;
    float* ws  = (float*)d_ws;

    // ws: num[32*4096] | den[32]+pad | qw[4096]  (~540 KB)
    qw_kernel<<<dim3(64), dim3(64), 0, stream>>>(qe, Wq_w, Wq_b, Wkv_w, ws);
    flash_partial<<<dim3(NUNIT), dim3(256), 0, stream>>>(x, ws);
    divide_kernel<<<dim3(128), dim3(256), 0, stream>>>(ws, out);
}

// Round 16
// 54.332 us; speedup vs baseline: 1.3545x; 1.3545x over previous
//
#include <hip/hip_runtime.h>

#define B_    32
#define S_    512
#define ND_   4096   // N*D = 64*64
#define ND4_  1024
#define SCH   16     // s-chunks per batch
#define CH    32     // rows per block (S_/SCH), processed cooperatively
#define NPH   (CH/2) // 2 rows per barrier phase
#define NUNIT (B_ * SCH)

typedef float f4 __attribute__((ext_vector_type(4)));
typedef float f2 __attribute__((ext_vector_type(2)));

// qw[n,d] = (sum_e (q_embed[n,:] . Wq_w[e,:] + Wq_b[e]) * Wkv_w[e,d]) / sqrt(D)
__global__ void qw_kernel(const float* __restrict__ qe, const float* __restrict__ Wq_w,
                          const float* __restrict__ Wq_b, const float* __restrict__ Wkv_w,
                          float* __restrict__ qw) {
    const int n = blockIdx.x;   // 64 blocks
    const int t = threadIdx.x;  // 64 threads
    __shared__ float qrow[64];
    float acc = Wq_b[t];
    const float* qen = qe + n * 64;
    const float* wqr = Wq_w + t * 64;   // q[n,e] = sum_d qe[n,d]*Wq_w[e,d] + b[e]
#pragma unroll 8
    for (int d = 0; d < 64; ++d) acc += qen[d] * wqr[d];
    qrow[t] = acc;
    __syncthreads();
    float s = 0.f;
#pragma unroll 8
    for (int e = 0; e < 64; ++e) s += qrow[e] * Wkv_w[e * 64 + t];  // k half only
    qw[n * 64 + t] = s * 0.125f;  // 1/sqrt(64)
}

// Cooperative-row flash, r12 structure but 512-thread blocks: thread t holds
// f4 slice k*512+t (k=0,1) -> ~70 live VGPRs -> 4 waves/SIMD (16 waves/CU,
// 2x r12's occupancy) at IDENTICAL traffic and pipeline depth. 2 rows per
// barrier phase, fixed-max softmax (m=8, clamp 52), raw s_barrier +
// lgkmcnt-only wait + sched_barrier(0) pin (rule #18). Parity-buffered red[2][8].
__global__ __launch_bounds__(512) void flash_partial(
    const float* __restrict__ x, const float* __restrict__ qw,
    float* __restrict__ po, float* __restrict__ pml) {
    const int blk = blockIdx.x;
    const int b   = blk >> 4;        // / SCH
    const int c   = blk & (SCH - 1);
    const int t   = threadIdx.x;     // 0..511
    const int w   = t >> 6;          // wave 0..7
    const int l   = t & 63;

    __shared__ f2 red[2][8];

    const f4* qw4 = (const f4*)qw;
    f4 qv[2];
#pragma unroll
    for (int k = 0; k < 2; ++k) qv[k] = qw4[k * 512 + t];

    f4 o[2];
#pragma unroll
    for (int k = 0; k < 2; ++k) o[k] = (f4)(0.f);
    float lsum = 0.f;

    const f4* xb = (const f4*)x + (size_t)(b * S_ + c * CH) * ND4_;

    f4 cur[2][2], nxt[2][2];
#pragma unroll
    for (int rr = 0; rr < 2; ++rr)
#pragma unroll
        for (int k = 0; k < 2; ++k) cur[rr][k] = xb[(size_t)rr * ND4_ + k * 512 + t];

    for (int ph = 0; ph < NPH; ++ph) {
        // prefetch next pair BEFORE the barrier region: rides in flight across it
        if (ph + 1 < NPH) {
            const f4* xn = xb + (size_t)(2 * ph + 2) * ND4_;
#pragma unroll
            for (int rr = 0; rr < 2; ++rr)
#pragma unroll
                for (int k = 0; k < 2; ++k) nxt[rr][k] = xn[(size_t)rr * ND4_ + k * 512 + t];
        }

        float pd0 = 0.f, pd1 = 0.f;
#pragma unroll
        for (int k = 0; k < 2; ++k) {
            pd0 += cur[0][k][0] * qv[k][0] + cur[0][k][1] * qv[k][1] +
                   cur[0][k][2] * qv[k][2] + cur[0][k][3] * qv[k][3];
            pd1 += cur[1][k][0] * qv[k][0] + cur[1][k][1] * qv[k][1] +
                   cur[1][k][2] * qv[k][2] + cur[1][k][3] * qv[k][3];
        }
#pragma unroll
        for (int off = 32; off > 0; off >>= 1) {
            pd0 += __shfl_xor(pd0, off, 64);
            pd1 += __shfl_xor(pd1, off, 64);
        }

        const int par = ph & 1;
        if (l == 0) { f2 v = { pd0, pd1 }; red[par][w] = v; }
        asm volatile("s_waitcnt lgkmcnt(0)" ::: "memory");  // red-write visible
        __builtin_amdgcn_s_barrier();
        __builtin_amdgcn_sched_barrier(0);                  // no hoist above barrier
        const f2 pr = (red[par][0] + red[par][1]) + (red[par][2] + red[par][3]) +
                      (red[par][4] + red[par][5]) + (red[par][6] + red[par][7]);

        const float e0 = __expf(fminf(pr[0] - 8.f, 52.f));  // fixed max; clamp dead for real data
        const float e1 = __expf(fminf(pr[1] - 8.f, 52.f));
        lsum += e0 + e1;
#pragma unroll
        for (int k = 0; k < 2; ++k) o[k] += e0 * cur[0][k] + e1 * cur[1][k];

        if (ph + 1 < NPH) {
#pragma unroll
            for (int rr = 0; rr < 2; ++rr)
#pragma unroll
                for (int k = 0; k < 2; ++k) cur[rr][k] = nxt[rr][k];
        }
    }

    // each thread's o[] is final for its slice; lsum is block-uniform
    f4* pob = (f4*)po + (size_t)blk * ND4_;
#pragma unroll
    for (int k = 0; k < 2; ++k) pob[k * 512 + t] = o[k];
    if (t == 0) pml[blk] = lsum;
}

// out[b,:] = (sum_c po_c) / (sum_c l_c)  — f4-vectorized, 128 blocks
__global__ __launch_bounds__(256) void combine_kernel(
    const float* __restrict__ po, const float* __restrict__ pml,
    float* __restrict__ out) {
    const int b    = blockIdx.x >> 2;   // 4 segments of 256 f4 cover ND4_
    const int seg  = blockIdx.x & 3;
    const int t    = threadIdx.x;
    const int idx4 = seg * 256 + t;
    __shared__ float sl[SCH];
    if (t < SCH) sl[t] = pml[b * SCH + t];
    __syncthreads();
    float L = 0.f;
    f4 acc = (f4)(0.f);
#pragma unroll
    for (int c = 0; c < SCH; ++c) {
        L   += sl[c];
        acc += ((const f4*)po)[(size_t)(b * SCH + c) * ND4_ + idx4];
    }
    ((f4*)out)[(size_t)b * ND4_ + idx4] = acc * (1.f / L);
}

extern "C" void kernel_launch(void* const* d_in, const int* in_sizes, int n_in,
                              void* d_out, int out_size, void* d_ws, size_t ws_size,
                              hipStream_t stream) {
    const float* x     = (const float*)d_in[0];
    const float* qe    = (const float*)d_in[1];
    const float* Wq_w  = (const float*)d_in[2];
    const float* Wq_b  = (const float*)d_in[3];
    const float* Wkv_w = (const float*)d_in[4];
    // d_in[5] = Wkv_b: shifts prod by a per-(b,s)-uniform constant -> softmax-invariant.
    float* out = (float*)d_out;

    // ws layout: qw[ND_] | pml[NUNIT] | po[NUNIT*ND_]  (~8.4 MB)
    float* qw  = (float*)d_ws;
    float* pml = qw + ND_;
    float* po  = pml + NUNIT;

    qw_kernel<<<dim3(64), dim3(64), 0, stream>>>(qe, Wq_w, Wq_b, Wkv_w, qw);
    flash_partial<<<dim3(NUNIT), dim3(512), 0, stream>>>(x, qw, po, pml);
    combine_kernel<<<dim3(B_ * 4), dim3(256), 0, stream>>>(po, pml, out);
}